// Round 8
// baseline (51.051 us; speedup 1.0000x reference)
//
#include <hip/hip_runtime.h>
#include <math.h>

// Disable FP contraction file-wide so every rounding step is the one we wrote;
// fmas are explicit via fmaf() where we want to mimic the XLA/Eigen dot chain.
#pragma clang fp contract(off)

#define VOCAB 4096
#define NPTS  32768          // 4 * 8192
#define NELEM 98304          // NPTS * 3
#define BLOCK 1024
#define NWAVE 16                     // waves per block
#define CPW   (VOCAB / NWAVE)        // 256 codes scanned per wave
#define PPL   2                      // points per lane
#define PTS_PER_BLOCK (64 * PPL)     // 128 points per block -> 256 blocks

// ---------------------------------------------------------------------------
// Kernel 0: pack the codebook as float4 (2*e0, 2*e1, 2*e2, ||e||^2) into
// workspace. Doubling is exact (power-of-2 scale), so the fma dot-chain on
// doubled values is bit-exactly 2*dot of the original chain; esq keeps the
// reference association (e0*e0 + e1*e1) + e2*e2.
// ---------------------------------------------------------------------------
__global__ __launch_bounds__(1024) void vq_prep(
    const float* __restrict__ embed, float4* __restrict__ gcodes)
{
  const int c = blockIdx.x * 1024 + threadIdx.x;
  float e0 = embed[3 * c + 0];
  float e1 = embed[3 * c + 1];
  float e2 = embed[3 * c + 2];
  float esq = (e0 * e0 + e1 * e1) + e2 * e2;
  gcodes[c] = make_float4(e0 + e0, e1 + e1, e2 + e2, esq);
}

// ---------------------------------------------------------------------------
// Kernel 1: nearest-code assignment + quant_st + idx + scatter (counts, sums)
// + SSE loss partial.
//
// Model history: r4/r6/r7 all pinned at 40-41 us across 2x changes in both
// LDS-read count and occupancy -> the LDS port never got cheaper (compiler
// reloads per eval at VGPR=36) and/or VALU issue is inflated. This round:
//  - DUAL-SOURCE code stream: even codes via broadcast ds_read_b128 from
//    LDS, odd codes via vector global loads from the packed L2-resident
//    copy (opaque VGPR zero in the address defeats scalarization -- the r5
//    K$ path is NOT taken). Halves LDS-port pressure; VMEM rides the
//    separate TA pipe, latency hidden under ~500 VALU cycles per body.
//  - Pre-doubled codes: d = (xsq - dot2) + esq, bit-identical to
//    (xsq - 2*dot) + esq, saves one v_mul per eval -> 8 VALU/eval.
//  - __launch_bounds__(1024,4): VGPR cap 128 (vs 36) so unroll-8's loads
//    stay in registers.
// Wave w scans codes [256w,256w+256) ascending (source alternates but values
// are bit-identical copies); wave ranges ascending + lexicographic (d,idx)
// combine => exact argmin first-min semantics (absmax 0 pedigree).
// ---------------------------------------------------------------------------
__global__ __launch_bounds__(BLOCK, 4) void vq_assign(
    const float* __restrict__ feats, const float4* __restrict__ gcodes,
    float* __restrict__ out_quant, float* __restrict__ out_idx,
    float* __restrict__ counts, float* __restrict__ sums,
    float* __restrict__ sse)
{
  extern __shared__ float4 codes[];        // [VOCAB] = 64 KiB dynamic
  __shared__ float dbuf[NWAVE][PPL][64];   // 8 KiB
  __shared__ int   ibuf[NWAVE][PPL][64];   // 8 KiB

  const int tid  = threadIdx.x;
  const int lane = tid & 63;
  const int wv   = tid >> 6;

  // Stage packed codebook into LDS (coalesced float4 copies).
  #pragma unroll
  for (int c = tid; c < VOCAB; c += BLOCK) codes[c] = gcodes[c];
  __syncthreads();

  // Lane owns points pbase+lane (slot 0) and pbase+64+lane (slot 1).
  const int pbase = blockIdx.x * PTS_PER_BLOCK;
  float px[PPL][3], xsq[PPL];
  #pragma unroll
  for (int s = 0; s < PPL; ++s) {
    const int p = pbase + s * 64 + lane;
    px[s][0] = feats[3 * p + 0];
    px[s][1] = feats[3 * p + 1];
    px[s][2] = feats[3 * p + 2];
    xsq[s] = (px[s][0] * px[s][0] + px[s][1] * px[s][1]) + px[s][2] * px[s][2];
  }

  float best[PPL] = {INFINITY, INFINITY};
  int   bidx[PPL] = {0, 0};

  const int cbase = wv * CPW;
  const float4* lc = codes + cbase;        // LDS stream (even k)
  // Opaque VGPR zero: compiler cannot prove uniformity -> vector global
  // loads (L1/L2 path), NOT s_load through the 16KB constant cache (r5 bug).
  int vz;
  asm volatile("v_mov_b32 %0, 0" : "=v"(vz));
  const float4* gcv = gcodes + cbase + vz; // global stream (odd k)

  #pragma unroll 8
  for (int k = 0; k < CPW; k += 2) {
    float4 eL = lc[k];                     // ds_read_b128, broadcast
    float4 eG = gcv[k + 1];                // global_load_dwordx4, L2-resident
    #pragma unroll
    for (int s = 0; s < PPL; ++s) {
      // dot2 = fma chain on pre-doubled codes == 2*dot bit-exactly
      float dotL = fmaf(px[s][2], eL.z, fmaf(px[s][1], eL.y, px[s][0] * eL.x));
      float dL = (xsq[s] - dotL) + eL.w;   // == (xsq - 2*dot) + esq
      if (dL < best[s]) { best[s] = dL; bidx[s] = cbase + k; }      // strict <
      float dotG = fmaf(px[s][2], eG.z, fmaf(px[s][1], eG.y, px[s][0] * eG.x));
      float dG = (xsq[s] - dotG) + eG.w;
      if (dG < best[s]) { best[s] = dG; bidx[s] = cbase + k + 1; }  // strict <
    }
  }

  #pragma unroll
  for (int s = 0; s < PPL; ++s) {
    dbuf[wv][s][lane] = best[s];
    ibuf[wv][s][lane] = bidx[s];
  }
  __syncthreads();

  if (wv == 0) {
    #pragma unroll
    for (int s = 0; s < PPL; ++s) {
      float b = best[s];
      int   bi = bidx[s];
      #pragma unroll
      for (int w = 1; w < NWAVE; ++w) {
        float od = dbuf[w][s][lane];
        int   oi = ibuf[w][s][lane];
        // lexicographic (d, idx): wave ranges ascending => first-min
        if (od < b || (od == b && oi < bi)) { b = od; bi = oi; }
      }

      const int p = pbase + s * 64 + lane;
      const float4 q = codes[bi];          // packed: (2e0,2e1,2e2,esq)
      const float q0 = 0.5f * q.x;         // exact halving -> original bits
      const float q1 = 0.5f * q.y;
      const float q2 = 0.5f * q.z;
      const float x0 = px[s][0], x1 = px[s][1], x2 = px[s][2];

      // quant_st = feats + (quant - feats), exactly as the reference does
      out_quant[3 * p + 0] = x0 + (q0 - x0);
      out_quant[3 * p + 1] = x1 + (q1 - x1);
      out_quant[3 * p + 2] = x2 + (q2 - x2);
      out_idx[p] = (float)bi;

      atomicAdd(&counts[bi], 1.0f);
      atomicAdd(&sums[3 * bi + 0], x0);
      atomicAdd(&sums[3 * bi + 1], x1);
      atomicAdd(&sums[3 * bi + 2], x2);

      float d0 = q0 - x0, d1 = q1 - x1, d2 = q2 - x2;
      float l = (d0 * d0 + d1 * d1) + d2 * d2;
      #pragma unroll
      for (int m = 1; m <= 32; m <<= 1) l += __shfl_xor(l, m, 64);
      if (lane == 0) atomicAdd(sse, l);
    }
  }
}

// ---------------------------------------------------------------------------
// Kernel 2: EMA update, global n-reduction, normalized embed, loss finalize.
// Single 1024-thread block; shuffle-based n reduction (1 barrier).
// ---------------------------------------------------------------------------
__global__ __launch_bounds__(1024) void vq_ema(
    const float* __restrict__ counts, const float* __restrict__ sums,
    const float* __restrict__ sse,
    const float* __restrict__ ema_cs, const float* __restrict__ ema_w,
    float* __restrict__ out_loss, float* __restrict__ out_ncs,
    float* __restrict__ out_nw, float* __restrict__ out_nemb)
{
  __shared__ float part[16];
  const int tid = threadIdx.x;
  const float DEC = 0.99f;
  const float OMD = (float)(1.0 - 0.99);
  const float EPS = 1e-5f;

  float ncs[4];
  float nw[12];
  float nsum = 0.0f;

  #pragma unroll
  for (int k = 0; k < 4; ++k) {
    int v = k * 1024 + tid;
    float t = DEC * ema_cs[v] + OMD * counts[v];
    ncs[k] = t;
    out_ncs[v] = t;
    nsum += t;
    #pragma unroll
    for (int d = 0; d < 3; ++d) {
      float w = DEC * ema_w[3 * v + d] + OMD * sums[3 * v + d];
      nw[3 * k + d] = w;
      out_nw[3 * v + d] = w;
    }
  }

  #pragma unroll
  for (int m = 1; m <= 32; m <<= 1) nsum += __shfl_xor(nsum, m, 64);
  if ((tid & 63) == 0) part[tid >> 6] = nsum;
  __syncthreads();

  float n = 0.0f;
  #pragma unroll
  for (int i = 0; i < 16; ++i) n += part[i];
  const float denom = n + (float)VOCAB * EPS;

  #pragma unroll
  for (int k = 0; k < 4; ++k) {
    int v = k * 1024 + tid;
    float cs = (ncs[k] + EPS) / denom * n;
    #pragma unroll
    for (int d = 0; d < 3; ++d)
      out_nemb[3 * v + d] = nw[3 * k + d] / cs;
  }

  if (tid == 0) {
    float m = sse[0] / (float)NELEM;
    out_loss[0] = m + 0.25f * m;   // mean((q-f)^2) + 0.25*mean((f-q)^2)
  }
}

// ---------------------------------------------------------------------------
extern "C" void kernel_launch(void* const* d_in, const int* in_sizes, int n_in,
                              void* d_out, int out_size, void* d_ws, size_t ws_size,
                              hipStream_t stream) {
  const float* feats  = (const float*)d_in[0];   // (4,8192,3)
  const float* embed  = (const float*)d_in[1];   // (4096,3)
  const float* ema_cs = (const float*)d_in[2];   // (4096,)
  const float* ema_w  = (const float*)d_in[3];   // (4096,3)

  float* out      = (float*)d_out;
  float* o_quant  = out;                       // 98304
  float* o_idx    = out + 98304;               // 32768
  float* o_loss   = out + 131072;              // 1
  float* o_ncs    = out + 131073;              // 4096
  float* o_nw     = out + 135169;              // 12288
  float* o_nemb   = out + 147457;              // 12288

  float* ws_counts = (float*)d_ws;             // 4096
  float* ws_sums   = ws_counts + VOCAB;        // 12288
  float* ws_sse    = ws_sums + 3 * VOCAB;      // 1
  // 16400 floats = 65600 B so far; 65600 % 16 == 0 -> gcodes is 16B-aligned
  float4* ws_gcodes = (float4*)((float*)d_ws + 16400);   // 4096 float4 = 64 KiB

  hipMemsetAsync(d_ws, 0, (size_t)(VOCAB * 4 + 1) * sizeof(float), stream);

  vq_prep<<<VOCAB / 1024, 1024, 0, stream>>>(embed, ws_gcodes);

  vq_assign<<<NPTS / PTS_PER_BLOCK, BLOCK, VOCAB * sizeof(float4), stream>>>(
      feats, ws_gcodes, o_quant, o_idx, ws_counts, ws_sums, ws_sse);

  vq_ema<<<1, 1024, 0, stream>>>(
      ws_counts, ws_sums, ws_sse, ema_cs, ema_w,
      o_loss, o_ncs, o_nw, o_nemb);
}